// Round 12
// baseline (764.704 us; speedup 1.0000x reference)
//
#include <hip/hip_runtime.h>
#include <math.h>

#define BB 2
#define LL 4096
#define DM 1024
#define DI 2048
#define NH 32
#define HD 64
#define NSTATE 64
#define CONVD 2176
#define RAWC 2208      // CONVD + NH
#define NC 16
#define CK 256
#define CTL 128        // conv l-tile per block

typedef __attribute__((ext_vector_type(8))) short bf16x8;
typedef __attribute__((ext_vector_type(8))) _Float16 f16x8;
typedef __attribute__((ext_vector_type(4))) float f32x4;

#define WAITVM(N) asm volatile("s_waitcnt vmcnt(" #N ")" ::: "memory")
#define WAITLGKM0 asm volatile("s_waitcnt lgkmcnt(0)" ::: "memory")

__device__ __forceinline__ float sigmoidf_(float x) { return 1.f / (1.f + expf(-x)); }
__device__ __forceinline__ float softplusf_(float x) { return (x > 20.f) ? x : log1pf(expf(x)); }

__device__ __forceinline__ unsigned short f2bf(float v) {
    unsigned u = __float_as_uint(v);
    unsigned r = (u + 0x7FFFu + ((u >> 16) & 1u)) >> 16;
    return (unsigned short)r;
}
__device__ __forceinline__ float bf2f(unsigned short h) {
    return __uint_as_float(((unsigned)h) << 16);
}

// swizzled index (shorts/halves) in a [64][64] 16-bit tile: 16B slot ^= row&7
__device__ __forceinline__ int swz(int row, int col) {
    return row * 64 + ((((col >> 3) ^ (row & 7)) << 3) | (col & 7));
}

typedef const __attribute__((address_space(1))) void gvoid_t;
typedef __attribute__((address_space(3))) void lvoid_t;
__device__ __forceinline__ void gload_lds16(const void* g, void* l) {
    __builtin_amdgcn_global_load_lds((gvoid_t*)g, (lvoid_t*)l, 16, 0, 0);
}

// ---------------- fp16 pack kernels ----------------

__global__ __launch_bounds__(256) void pack_a16(const float* __restrict__ X,
                                                _Float16* __restrict__ Y, int n) {
    int idx = blockIdx.x * 256 + threadIdx.x;
    if (idx < n) Y[idx] = (_Float16)X[idx];
}

// W (N x K) -> Y (Npad x K), zero-padded rows
__global__ __launch_bounds__(256) void pack_w16(const float* __restrict__ W,
                                                _Float16* __restrict__ Y,
                                                int N, int Npad, int K) {
    int idx = blockIdx.x * 256 + threadIdx.x;
    if (idx >= Npad * K) return;
    int n = idx / K;
    Y[idx] = (n < N) ? (_Float16)W[idx] : (_Float16)0.f;
}

// ---------------- fp16 MFMA GEMM: C[m,n] = sum_k A[m,k]*B[n,k] ----------------
__global__ __launch_bounds__(256) void gemm_f16(const _Float16* __restrict__ A,
                                                const _Float16* __restrict__ B,
                                                float* __restrict__ C,
                                                int M, int N, int K) {
    __shared__ _Float16 As[128 * 32];
    __shared__ _Float16 Bs[128 * 32];
    int tid = threadIdx.x;
    int lane = tid & 63;
    int w = tid >> 6;
    int wr = w >> 1, wc = w & 1;
    int n0 = blockIdx.x * 128, m0 = blockIdx.y * 128;
    f32x4 acc[4][4] = {};

    for (int k0 = 0; k0 < K; k0 += 32) {
        #pragma unroll
        for (int p = 0; p < 2; ++p) {
            int s = p * 256 + tid;
            int row = s >> 2;
            int sub = (s & 3) ^ ((row >> 1) & 3);
            gload_lds16(A + (size_t)(m0 + row) * K + k0 + sub * 8, &As[s * 8]);
            gload_lds16(B + (size_t)(n0 + row) * K + k0 + sub * 8, &Bs[s * 8]);
        }
        __syncthreads();
        f16x8 af[4], bfv[4];
        #pragma unroll
        for (int i = 0; i < 4; ++i) {
            int rowA = wr * 64 + i * 16 + (lane & 15);
            int slotA = (lane >> 4) ^ ((rowA >> 1) & 3);
            af[i] = *(const f16x8*)&As[rowA * 32 + slotA * 8];
            int rowB = wc * 64 + i * 16 + (lane & 15);
            int slotB = (lane >> 4) ^ ((rowB >> 1) & 3);
            bfv[i] = *(const f16x8*)&Bs[rowB * 32 + slotB * 8];
        }
        #pragma unroll
        for (int i = 0; i < 4; ++i)
            #pragma unroll
            for (int j = 0; j < 4; ++j)
                acc[i][j] = __builtin_amdgcn_mfma_f32_16x16x32_f16(af[i], bfv[j], acc[i][j], 0, 0, 0);
        __syncthreads();
    }

    #pragma unroll
    for (int i = 0; i < 4; ++i) {
        int mbase = m0 + wr * 64 + i * 16 + (lane >> 4) * 4;
        #pragma unroll
        for (int j = 0; j < 4; ++j) {
            int n = n0 + wc * 64 + j * 16 + (lane & 15);
            if (n < N) {
                #pragma unroll
                for (int r = 0; r < 4; ++r)
                    C[(size_t)(mbase + r) * N + n] = acc[i][j][r];
            }
        }
    }
}

// ---------------- conv / dt ----------------

// Sliding-window depthwise conv7 + bias + SiLU. Thread owns channel ch, walks
// CTL consecutive l; each raw element loaded exactly once (coalesced in ch).
__global__ __launch_bounds__(256) void conv_silu(const float* __restrict__ raw,
                                                 const float* __restrict__ cw,
                                                 const float* __restrict__ cb,
                                                 float* __restrict__ xbc) {
    int ch = blockIdx.x * 256 + threadIdx.x;
    if (ch >= CONVD) return;
    int l0 = blockIdx.y * CTL;
    int b = blockIdx.z;
    float wt[7];
    #pragma unroll
    for (int j = 0; j < 7; ++j) wt[j] = cw[ch * 7 + j];
    float bias = cb[ch];
    const float* rbase = raw + (size_t)b * LL * RAWC + ch;
    float win[7];
    #pragma unroll
    for (int j = 0; j < 6; ++j) {
        int lj = l0 - 3 + j;
        win[j] = (lj >= 0 && lj < LL) ? rbase[(size_t)lj * RAWC] : 0.f;
    }
    size_t obase = ((size_t)b * LL + l0) * CONVD + ch;
    for (int i = 0; i < CTL; ++i) {
        int lj = l0 + i + 3;
        win[6] = (lj < LL) ? rbase[(size_t)lj * RAWC] : 0.f;
        float acc = bias;
        #pragma unroll
        for (int j = 0; j < 7; ++j) acc += wt[j] * win[j];
        xbc[obase + (size_t)i * CONVD] = acc * sigmoidf_(acc);
        #pragma unroll
        for (int j = 0; j < 6; ++j) win[j] = win[j + 1];
    }
}

__global__ __launch_bounds__(256) void dt_kernel(const float* __restrict__ raw,
                                                 const float* __restrict__ dt_bias,
                                                 float* __restrict__ dtb) {
    int idx = blockIdx.x * 256 + threadIdx.x;
    if (idx >= BB * LL * NH) return;
    int h = idx & 31;
    int row = idx >> 5;
    float x = raw[(size_t)row * RAWC + CONVD + h] + dt_bias[h];
    dtb[idx] = softplusf_(x);
}

// ---------------- SSD ----------------

__device__ __forceinline__ float block_scan256(float v, float* sc, int tid) {
    sc[tid] = v;
    __syncthreads();
    for (int off = 1; off < 256; off <<= 1) {
        float t = 0.f;
        if (tid >= off) t = sc[tid - off];
        __syncthreads();
        sc[tid] += t;
        __syncthreads();
    }
    return sc[tid];
}

// G' tiles: G[l,s] = sum_n C[l,n]*B[s,n] per (bc), bf16 hi/lo, diag-masked,
// stored PRE-SWIZZLED so s3 can DMA them straight into LDS.
__global__ __launch_bounds__(256) void g_mfma(const float* __restrict__ xbc,
                                              unsigned short* __restrict__ Gth,
                                              unsigned short* __restrict__ Gtl,
                                              int dir) {
    int lt = blockIdx.x, st = blockIdx.y, bc = blockIdx.z;
    if (st > lt) return;
    int b = bc / NC, c = bc % NC;
    int tid = threadIdx.x, lane = tid & 63, w = tid >> 6;
    __shared__ short Ch[4096], Cl[4096], Bh[4096], Bl[4096];
    #pragma unroll
    for (int i = 0; i < 16; ++i) {
        int e = tid + i * 256;
        int r = e >> 6, q = e & 63;
        int il = c * CK + lt * 64 + r;
        int tl = dir ? (LL - 1 - il) : il;
        float cv = xbc[((size_t)b * LL + tl) * CONVD + DI + NSTATE + q];
        unsigned short chh = f2bf(cv);
        Ch[swz(r, q)] = chh;
        Cl[swz(r, q)] = f2bf(cv - bf2f(chh));
        int is = c * CK + st * 64 + r;
        int ts = dir ? (LL - 1 - is) : is;
        float bv = xbc[((size_t)b * LL + ts) * CONVD + DI + q];
        unsigned short bhh = f2bf(bv);
        Bh[swz(r, q)] = bhh;
        Bl[swz(r, q)] = f2bf(bv - bf2f(bhh));
    }
    __syncthreads();
    f32x4 acc[4] = {};
    #pragma unroll
    for (int kk = 0; kk < 64; kk += 32) {
        int arow = w * 16 + (lane & 15);
        int aslot = ((kk >> 3) + (lane >> 4)) ^ (arow & 7);
        bf16x8 ah = *(const bf16x8*)&Ch[arow * 64 + aslot * 8];
        bf16x8 al = *(const bf16x8*)&Cl[arow * 64 + aslot * 8];
        #pragma unroll
        for (int j = 0; j < 4; ++j) {
            int brow = j * 16 + (lane & 15);
            int bslot = ((kk >> 3) + (lane >> 4)) ^ (brow & 7);
            bf16x8 bh = *(const bf16x8*)&Bh[brow * 64 + bslot * 8];
            bf16x8 bl = *(const bf16x8*)&Bl[brow * 64 + bslot * 8];
            acc[j] = __builtin_amdgcn_mfma_f32_16x16x32_bf16(ah, bh, acc[j], 0, 0, 0);
            acc[j] = __builtin_amdgcn_mfma_f32_16x16x32_bf16(ah, bl, acc[j], 0, 0, 0);
            acc[j] = __builtin_amdgcn_mfma_f32_16x16x32_bf16(al, bh, acc[j], 0, 0, 0);
        }
    }
    size_t tbase = ((size_t)bc * 10 + (size_t)(lt * (lt + 1) / 2 + st)) * 4096;
    #pragma unroll
    for (int j = 0; j < 4; ++j)
        #pragma unroll
        for (int rr = 0; rr < 4; ++rr) {
            int row = w * 16 + (lane >> 4) * 4 + rr;
            int col = j * 16 + (lane & 15);
            float g = acc[j][rr];
            if (lt == st && (col + dir > row)) g = 0.f;
            unsigned short hi = f2bf(g);
            int si = swz(row, col);
            Gth[tbase + si] = hi;
            Gtl[tbase + si] = f2bf(g - bf2f(hi));
        }
}

// states[p,n] = sum_s (w[s]*X[s,p]) * B[s,n]  via MFMA
__global__ __launch_bounds__(256) void s1_mfma(const float* __restrict__ xbc,
                                               const float* __restrict__ dtb,
                                               const float* __restrict__ A_log,
                                               float* __restrict__ states,
                                               float* __restrict__ csum, int dir) {
    int h = blockIdx.x, c = blockIdx.y, b = blockIdx.z;
    int tid = threadIdx.x, lane = tid & 63, w = tid >> 6;
    __shared__ float sc[256];
    {
        int gi = c * CK + tid;
        int t = dir ? (LL - 1 - gi) : gi;
        float A = -expf(A_log[h]);
        float dtv = dtb[((size_t)b * LL + t) * NH + h];
        float acum = block_scan256(dtv * A, sc, tid);
        float cs = sc[255];
        if (tid == 0) csum[(b * NC + c) * NH + h] = cs;
        float wgt = expf(cs - acum) * dtv;
        __syncthreads();
        sc[tid] = wgt;
        __syncthreads();
    }
    __shared__ short XTh[4096], XTl[4096], BTh[4096], BTl[4096];
    f32x4 acc[4] = {};
    #pragma unroll
    for (int st = 0; st < 4; ++st) {
        #pragma unroll
        for (int i = 0; i < 16; ++i) {
            int e = tid + i * 256;
            int r = e >> 6, q = e & 63;
            int gs = c * CK + st * 64 + r;
            int ts = dir ? (LL - 1 - gs) : gs;
            size_t rowb = ((size_t)b * LL + ts) * CONVD;
            float xv = xbc[rowb + h * 64 + q] * sc[st * 64 + r];
            unsigned short xh = f2bf(xv);
            XTh[swz(q, r)] = xh;
            XTl[swz(q, r)] = f2bf(xv - bf2f(xh));
            float bv = xbc[rowb + DI + q];
            unsigned short bh_ = f2bf(bv);
            BTh[swz(q, r)] = bh_;
            BTl[swz(q, r)] = f2bf(bv - bf2f(bh_));
        }
        __syncthreads();
        #pragma unroll
        for (int kk = 0; kk < 64; kk += 32) {
            int arow = w * 16 + (lane & 15);
            int aslot = ((kk >> 3) + (lane >> 4)) ^ (arow & 7);
            bf16x8 ah = *(const bf16x8*)&XTh[arow * 64 + aslot * 8];
            bf16x8 al = *(const bf16x8*)&XTl[arow * 64 + aslot * 8];
            #pragma unroll
            for (int j = 0; j < 4; ++j) {
                int brow = j * 16 + (lane & 15);
                int bslot = ((kk >> 3) + (lane >> 4)) ^ (brow & 7);
                bf16x8 bh = *(const bf16x8*)&BTh[brow * 64 + bslot * 8];
                bf16x8 bl = *(const bf16x8*)&BTl[brow * 64 + bslot * 8];
                acc[j] = __builtin_amdgcn_mfma_f32_16x16x32_bf16(ah, bh, acc[j], 0, 0, 0);
                acc[j] = __builtin_amdgcn_mfma_f32_16x16x32_bf16(ah, bl, acc[j], 0, 0, 0);
                acc[j] = __builtin_amdgcn_mfma_f32_16x16x32_bf16(al, bh, acc[j], 0, 0, 0);
            }
        }
        __syncthreads();
    }
    size_t base = (((size_t)(b * NC + c) * NH + h)) * 4096;
    #pragma unroll
    for (int j = 0; j < 4; ++j)
        #pragma unroll
        for (int rr = 0; rr < 4; ++rr) {
            int p = w * 16 + (lane >> 4) * 4 + rr;
            int n = j * 16 + (lane & 15);
            states[base + p * 64 + n] = acc[j][rr];
        }
}

__global__ __launch_bounds__(256) void s2_scan(float* __restrict__ states,
                                               const float* __restrict__ csum) {
    int h = blockIdx.x, b = blockIdx.y, eo = blockIdx.z;
    int e = eo * 256 + threadIdx.x;
    float run = 0.f;
    for (int z = 0; z < NC; ++z) {
        size_t base = (((size_t)(b * NC + z) * NH + h)) * (64 * 64);
        float s = states[base + e];
        states[base + e] = run;
        float g = expf(csum[(b * NC + z) * NH + h]);
        run = run * g + s;
    }
}

// Pipelined s3 v2: 2-slot G ring + 2-slot X dbuf -> 68 KB LDS -> 2 blocks/CU.
// G per-wave counted-vmcnt (barrier-free); X transitions use 3 raw lgkm-barriers.
__global__ __launch_bounds__(256, 2) void s3_pipe(const float* __restrict__ xbc,
                                                  const float* __restrict__ dtb,
                                                  const float* __restrict__ A_log,
                                                  const unsigned short* __restrict__ Gth,
                                                  const unsigned short* __restrict__ Gtl,
                                                  const float* __restrict__ prev,
                                                  float* __restrict__ y, int dir, int beta) {
    int h = blockIdx.x, bc = blockIdx.y;
    int b = bc / NC, c = bc % NC;
    int tid = threadIdx.x, lane = tid & 63, w = tid >> 6;

    __shared__ short Xh[2][4096], Xl[2][4096];   // 32 KB: (Ein∘X)^T dbuf
    __shared__ short Gh[2][4096], Gl[2][4096];   // 32 KB: G tile ring
    __shared__ float sEl[256], sEin[256];

    // scan -> El, Ein (sEl doubles as scan scratch)
    {
        int gi = c * CK + tid;
        int t = dir ? (LL - 1 - gi) : gi;
        float A = -expf(A_log[h]);
        float dtv = dtb[((size_t)b * LL + t) * NH + h];
        float acum = block_scan256(dtv * A, sEl, tid);
        sEl[tid] = expf(acum);
        sEin[tid] = expf(-acum) * dtv;
    }
    __syncthreads();

    // per-wave G-tile slice DMA: wave w owns rows [w*16,(w+1)*16) = shorts [w*1024,+1024)
    constexpr int tri_[10] = {0, 1, 3, 6, 2, 4, 7, 5, 8, 9};
    auto issueA = [&](int i) {
        size_t tb = ((size_t)bc * 10 + tri_[i]) * 4096;
        int slot = i & 1;
        int o = w * 1024 + lane * 8;
        gload_lds16(Gth + tb + o,       &Gh[slot][o]);
        gload_lds16(Gth + tb + o + 512, &Gh[slot][o + 512]);
        gload_lds16(Gtl + tb + o,       &Gl[slot][o]);
        gload_lds16(Gtl + tb + o + 512, &Gl[slot][o + 512]);
    };
    // stage (Ein∘X)^T tile st into slot st&1 (block-cooperative)
    auto stageX = [&](int st) {
        int slot = st & 1;
        #pragma unroll
        for (int i2 = 0; i2 < 16; ++i2) {
            int e = tid + i2 * 256;
            int r = e >> 6, q = e & 63;
            int gs = c * CK + st * 64 + r;
            int ts = dir ? (LL - 1 - gs) : gs;
            float xv = xbc[((size_t)b * LL + ts) * CONVD + h * 64 + q] * sEin[st * 64 + r];
            unsigned short xh = f2bf(xv);
            Xh[slot][swz(q, r)] = xh;
            Xl[slot][swz(q, r)] = f2bf(xv - bf2f(xh));
        }
    };

    issueA(0); issueA(1);   // 8 loads in flight per wave
    stageX(0);              // slot 0

    // lgkm-only wait + raw barrier: X[0] visible, G loads stay outstanding
    __builtin_amdgcn_sched_barrier(0);
    WAITLGKM0;
    __builtin_amdgcn_s_barrier();

    f32x4 acc[4][4] = {};
    constexpr int ph_lq[10] = {0, 1, 2, 3, 1, 2, 3, 2, 3, 3};
    constexpr int ph_st[10] = {0, 0, 0, 0, 1, 1, 1, 2, 2, 3};
    #pragma unroll
    for (int i = 0; i < 10; ++i) {
        const int lq = ph_lq[i], st = ph_st[i], slot = i & 1, xslot = st & 1;
        // st transition: X[st] was staged since last barrier; old slot retired
        if (i == 4 || i == 7 || i == 9) {
            __builtin_amdgcn_sched_barrier(0);
            WAITLGKM0;
            __builtin_amdgcn_s_barrier();
        }
        if (i < 9) { WAITVM(4); }   // A(i) landed; A(i+1) in flight
        else       { WAITVM(0); }
        __builtin_amdgcn_sched_barrier(0);
        int arow = w * 16 + (lane & 15);
        int s0 = (lane >> 4) ^ (arow & 7);
        int s1 = (4 + (lane >> 4)) ^ (arow & 7);
        bf16x8 ah0 = *(const bf16x8*)&Gh[slot][arow * 64 + s0 * 8];
        bf16x8 al0 = *(const bf16x8*)&Gl[slot][arow * 64 + s0 * 8];
        bf16x8 ah1 = *(const bf16x8*)&Gh[slot][arow * 64 + s1 * 8];
        bf16x8 al1 = *(const bf16x8*)&Gl[slot][arow * 64 + s1 * 8];
        bf16x8 bh0[4], bl0[4], bh1[4], bl1[4];
        #pragma unroll
        for (int j = 0; j < 4; ++j) {
            int brow = j * 16 + (lane & 15);
            int t0 = (lane >> 4) ^ (brow & 7);
            int t1 = (4 + (lane >> 4)) ^ (brow & 7);
            bh0[j] = *(const bf16x8*)&Xh[xslot][brow * 64 + t0 * 8];
            bl0[j] = *(const bf16x8*)&Xl[xslot][brow * 64 + t0 * 8];
            bh1[j] = *(const bf16x8*)&Xh[xslot][brow * 64 + t1 * 8];
            bl1[j] = *(const bf16x8*)&Xl[xslot][brow * 64 + t1 * 8];
        }
        WAITLGKM0;                           // ds_reads serviced before slot reuse
        __builtin_amdgcn_sched_barrier(0);
        if (i + 2 < 10) issueA(i + 2);       // overwrites G slot i&1 (just read)
        __builtin_amdgcn_sched_barrier(0);
        // stage next X tile during the first phase of each st run
        if (i == 0)      stageX(1);
        else if (i == 4) stageX(2);
        else if (i == 7) stageX(3);
        #pragma unroll
        for (int j = 0; j < 4; ++j) {
            acc[lq][j] = __builtin_amdgcn_mfma_f32_16x16x32_bf16(ah0, bh0[j], acc[lq][j], 0, 0, 0);
            acc[lq][j] = __builtin_amdgcn_mfma_f32_16x16x32_bf16(ah0, bl0[j], acc[lq][j], 0, 0, 0);
            acc[lq][j] = __builtin_amdgcn_mfma_f32_16x16x32_bf16(al0, bh0[j], acc[lq][j], 0, 0, 0);
            acc[lq][j] = __builtin_amdgcn_mfma_f32_16x16x32_bf16(ah1, bh1[j], acc[lq][j], 0, 0, 0);
            acc[lq][j] = __builtin_amdgcn_mfma_f32_16x16x32_bf16(ah1, bl1[j], acc[lq][j], 0, 0, 0);
            acc[lq][j] = __builtin_amdgcn_mfma_f32_16x16x32_bf16(al1, bh1[j], acc[lq][j], 0, 0, 0);
        }
    }

    // ---- Y_off: A = C(lq) (dbuf in G slots 0/1), B-op = prev (in X slot 0) ----
    __syncthreads();   // vmcnt already 0; full barrier before slot reuse
    {
        size_t pbase = ((size_t)bc * NH + h) * 4096;
        #pragma unroll
        for (int i2 = 0; i2 < 16; ++i2) {
            int e = tid + i2 * 256;
            int r = e >> 6, q = e & 63;
            float pv = prev[pbase + r * 64 + q];
            unsigned short ph = f2bf(pv);
            Xh[0][swz(r, q)] = ph;
            Xl[0][swz(r, q)] = f2bf(pv - bf2f(ph));
            int il = c * CK + r;
            int tl = dir ? (LL - 1 - il) : il;
            float cv = xbc[((size_t)b * LL + tl) * CONVD + DI + NSTATE + q];
            unsigned short chh = f2bf(cv);
            Gh[0][swz(r, q)] = chh;
            Gl[0][swz(r, q)] = f2bf(cv - bf2f(chh));
        }
        __syncthreads();
        #pragma unroll
        for (int lq = 0; lq < 4; ++lq) {
            if (lq < 3) {
                #pragma unroll
                for (int i2 = 0; i2 < 16; ++i2) {
                    int e = tid + i2 * 256;
                    int r = e >> 6, q = e & 63;
                    int il = c * CK + (lq + 1) * 64 + r;
                    int tl = dir ? (LL - 1 - il) : il;
                    float cv = xbc[((size_t)b * LL + tl) * CONVD + DI + NSTATE + q];
                    unsigned short chh = f2bf(cv);
                    Gh[(lq + 1) & 1][swz(r, q)] = chh;
                    Gl[(lq + 1) & 1][swz(r, q)] = f2bf(cv - bf2f(chh));
                }
            }
            int arow = w * 16 + (lane & 15);
            int s0 = (lane >> 4) ^ (arow & 7);
            int s1 = (4 + (lane >> 4)) ^ (arow & 7);
            bf16x8 ah0 = *(const bf16x8*)&Gh[lq & 1][arow * 64 + s0 * 8];
            bf16x8 al0 = *(const bf16x8*)&Gl[lq & 1][arow * 64 + s0 * 8];
            bf16x8 ah1 = *(const bf16x8*)&Gh[lq & 1][arow * 64 + s1 * 8];
            bf16x8 al1 = *(const bf16x8*)&Gl[lq & 1][arow * 64 + s1 * 8];
            #pragma unroll
            for (int j = 0; j < 4; ++j) {
                int brow = j * 16 + (lane & 15);
                int t0 = (lane >> 4) ^ (brow & 7);
                int t1 = (4 + (lane >> 4)) ^ (brow & 7);
                bf16x8 bh0 = *(const bf16x8*)&Xh[0][brow * 64 + t0 * 8];
                bf16x8 bl0 = *(const bf16x8*)&Xl[0][brow * 64 + t0 * 8];
                bf16x8 bh1 = *(const bf16x8*)&Xh[0][brow * 64 + t1 * 8];
                bf16x8 bl1 = *(const bf16x8*)&Xl[0][brow * 64 + t1 * 8];
                acc[lq][j] = __builtin_amdgcn_mfma_f32_16x16x32_bf16(ah0, bh0, acc[lq][j], 0, 0, 0);
                acc[lq][j] = __builtin_amdgcn_mfma_f32_16x16x32_bf16(ah0, bl0, acc[lq][j], 0, 0, 0);
                acc[lq][j] = __builtin_amdgcn_mfma_f32_16x16x32_bf16(al0, bh0, acc[lq][j], 0, 0, 0);
                acc[lq][j] = __builtin_amdgcn_mfma_f32_16x16x32_bf16(ah1, bh1, acc[lq][j], 0, 0, 0);
                acc[lq][j] = __builtin_amdgcn_mfma_f32_16x16x32_bf16(ah1, bl1, acc[lq][j], 0, 0, 0);
                acc[lq][j] = __builtin_amdgcn_mfma_f32_16x16x32_bf16(al1, bh1, acc[lq][j], 0, 0, 0);
            }
            __syncthreads();
        }
    }

    // epilogue: scale by El[l], store/accumulate
    #pragma unroll
    for (int lq = 0; lq < 4; ++lq)
        #pragma unroll
        for (int j = 0; j < 4; ++j)
            #pragma unroll
            for (int rr = 0; rr < 4; ++rr) {
                int ll = lq * 64 + w * 16 + (lane >> 4) * 4 + rr;
                int il = c * CK + ll;
                int tl = dir ? (LL - 1 - il) : il;
                size_t yb = ((size_t)b * LL + tl) * DI + h * 64 + j * 16 + (lane & 15);
                float v = sEl[ll] * acc[lq][j][rr];
                if (beta) y[yb] += v;
                else      y[yb]  = v;
            }
}

// RMSNorm + silu(z) gate, fused fp16 output (feeds out_proj GEMM directly).
__global__ __launch_bounds__(256) void norm_gate16(const float* __restrict__ zbuf,
                                                   const float* __restrict__ norm_w,
                                                   const float* __restrict__ y,
                                                   _Float16* __restrict__ y16) {
    int row = blockIdx.x;
    int tid = threadIdx.x;
    float ss = 0.f;
    size_t yb = (size_t)row * DI;
    for (int i = tid; i < DI; i += 256) {
        float v = y[yb + i];
        ss += v * v;
    }
    #pragma unroll
    for (int off = 32; off > 0; off >>= 1) ss += __shfl_down(ss, off, 64);
    __shared__ float red[4];
    if ((tid & 63) == 0) red[tid >> 6] = ss;
    __syncthreads();
    float tot = red[0] + red[1] + red[2] + red[3];
    float rstd = rsqrtf(tot / DI + 1e-5f);
    for (int i = tid; i < DI; i += 256) {
        float z = zbuf[yb + i];
        float g = z * sigmoidf_(z);
        y16[yb + i] = (_Float16)(y[yb + i] * rstd * norm_w[i] * g);
    }
}

extern "C" void kernel_launch(void* const* d_in, const int* in_sizes, int n_in,
                              void* d_out, int out_size, void* d_ws, size_t ws_size,
                              hipStream_t stream) {
    const float* u          = (const float*)d_in[0];
    const float* in_proj_w  = (const float*)d_in[1];
    const float* conv_w     = (const float*)d_in[2];
    const float* conv_b     = (const float*)d_in[3];
    const float* dt_bias    = (const float*)d_in[4];
    const float* A_log      = (const float*)d_in[5];
    const float* norm_w     = (const float*)d_in[6];
    const float* out_proj_w = (const float*)d_in[7];
    float* out = (float*)d_out;

    float* ws  = (float*)d_ws;
    float* z   = ws;                               // 16,777,216 f
    float* raw = z + (size_t)BB * LL * DI;         // 18,087,936 f
    float* xbc = raw + (size_t)BB * LL * RAWC;     // 17,825,792 f
    float* y   = raw;                              // alias: raw dead after conv+dt

    // fp16 pack buffers in dead regions:
    _Float16* u16    = (_Float16*)d_out;                 // 16.8 MB (d_out free pre-SSD)
    _Float16* w16z   = (_Float16*)xbc;                   // 4.2 MB (xbc not yet live)
    _Float16* w16raw = w16z + (size_t)2048 * 1024;       // 4.7 MB
    // post-SSD (xbc dead): out_proj weight + fused-norm fp16 y
    _Float16* w16out = (_Float16*)xbc;                   // 1024x2048 = 4.2 MB
    _Float16* y16    = w16out + (size_t)1024 * 2048;     // 8192x2048 = 33.5 MB (fits in xbc's 71 MB)

    // SSD scratch in d_out (u16 dead by then; overwritten by final GEMM at end)
    float* states        = (float*)d_out;                         // 4,194,304 f
    unsigned short* Gth  = (unsigned short*)(states + 4194304);   // 2,621,440 sh
    unsigned short* Gtl  = Gth + 2621440;                         // 2,621,440 sh
    float* dtb           = (float*)(Gtl + 2621440);               //   262,144 f
    float* csum          = dtb + 262144;                          //     1,024 f
    float* prev          = states;

    dim3 blk(256);
    int M = BB * LL;

    // 0) fp16 packs for in_proj
    pack_a16<<<(M * DM + 255) / 256, blk, 0, stream>>>(u, u16, M * DM);
    pack_w16<<<(2048 * DM + 255) / 256, blk, 0, stream>>>(in_proj_w, w16z, 2048, 2048, DM);
    pack_w16<<<(2304 * DM + 255) / 256, blk, 0, stream>>>(in_proj_w + (size_t)DI * DM, w16raw, RAWC, 2304, DM);
    // 1) in_proj GEMMs (fp16)
    gemm_f16<<<dim3(2048 / 128, M / 128), blk, 0, stream>>>(u16, w16z, z, M, 2048, DM);
    gemm_f16<<<dim3(2304 / 128, M / 128), blk, 0, stream>>>(u16, w16raw, raw, M, RAWC, DM);
    // 2) sliding-window conv + silu ; 3) dt
    conv_silu<<<dim3((CONVD + 255) / 256, LL / CTL, BB), blk, 0, stream>>>(raw, conv_w, conv_b, xbc);
    dt_kernel<<<(BB * LL * NH + 255) / 256, blk, 0, stream>>>(raw, dt_bias, dtb);
    // 4) bidirectional SSD
    for (int dir = 0; dir < 2; ++dir) {
        g_mfma<<<dim3(4, 4, BB * NC), blk, 0, stream>>>(xbc, Gth, Gtl, dir);
        s1_mfma<<<dim3(NH, NC, BB), blk, 0, stream>>>(xbc, dtb, A_log, states, csum, dir);
        s2_scan<<<dim3(NH, BB, 16), blk, 0, stream>>>(states, csum);
        s3_pipe<<<dim3(NH, BB * NC), blk, 0, stream>>>(xbc, dtb, A_log, Gth, Gtl, prev, y, dir, dir);
    }
    // 5) RMSNorm + gate, fused fp16 pack of y
    norm_gate16<<<M, blk, 0, stream>>>(z, norm_w, y, y16);
    // 6) out_proj (fp16)
    pack_a16<<<(DM * DI + 255) / 256, blk, 0, stream>>>(out_proj_w, w16out, DM * DI);
    gemm_f16<<<dim3(1024 / 128, M / 128), blk, 0, stream>>>(y16, w16out, out, M, DM, DI);
}

// Round 14
// 629.583 us; speedup vs baseline: 1.2146x; 1.2146x over previous
//
#include <hip/hip_runtime.h>
#include <math.h>

#define BB 2
#define LL 4096
#define DM 1024
#define DI 2048
#define NH 32
#define HD 64
#define NSTATE 64
#define CONVD 2176
#define RAWC 2208      // CONVD + NH
#define NC 16
#define CK 256
#define CTL 128        // conv l-tile per block

typedef __attribute__((ext_vector_type(8))) short bf16x8;
typedef __attribute__((ext_vector_type(8))) _Float16 f16x8;
typedef __attribute__((ext_vector_type(4))) float f32x4;

__device__ __forceinline__ float sigmoidf_(float x) { return 1.f / (1.f + expf(-x)); }
__device__ __forceinline__ float softplusf_(float x) { return (x > 20.f) ? x : log1pf(expf(x)); }

__device__ __forceinline__ unsigned short f2bf(float v) {
    unsigned u = __float_as_uint(v);
    unsigned r = (u + 0x7FFFu + ((u >> 16) & 1u)) >> 16;
    return (unsigned short)r;
}
__device__ __forceinline__ float bf2f(unsigned short h) {
    return __uint_as_float(((unsigned)h) << 16);
}

// swizzled index (shorts/halves) in a [64][64] 16-bit tile: 16B slot ^= row&7
__device__ __forceinline__ int swz(int row, int col) {
    return row * 64 + ((((col >> 3) ^ (row & 7)) << 3) | (col & 7));
}

typedef const __attribute__((address_space(1))) void gvoid_t;
typedef __attribute__((address_space(3))) void lvoid_t;
__device__ __forceinline__ void gload_lds16(const void* g, void* l) {
    __builtin_amdgcn_global_load_lds((gvoid_t*)g, (lvoid_t*)l, 16, 0, 0);
}

// ---------------- fp16 pack kernels ----------------

__global__ __launch_bounds__(256) void pack_a16(const float* __restrict__ X,
                                                _Float16* __restrict__ Y, int n) {
    int idx = blockIdx.x * 256 + threadIdx.x;
    if (idx < n) Y[idx] = (_Float16)X[idx];
}

// W (N x K) -> Y (Npad x K), zero-padded rows
__global__ __launch_bounds__(256) void pack_w16(const float* __restrict__ W,
                                                _Float16* __restrict__ Y,
                                                int N, int Npad, int K) {
    int idx = blockIdx.x * 256 + threadIdx.x;
    if (idx >= Npad * K) return;
    int n = idx / K;
    Y[idx] = (n < N) ? (_Float16)W[idx] : (_Float16)0.f;
}

// ---------------- fp16 MFMA GEMM: C[m,n] = sum_k A[m,k]*B[n,k] ----------------
__global__ __launch_bounds__(256) void gemm_f16(const _Float16* __restrict__ A,
                                                const _Float16* __restrict__ B,
                                                float* __restrict__ C,
                                                int M, int N, int K) {
    __shared__ _Float16 As[128 * 32];
    __shared__ _Float16 Bs[128 * 32];
    int tid = threadIdx.x;
    int lane = tid & 63;
    int w = tid >> 6;
    int wr = w >> 1, wc = w & 1;
    int n0 = blockIdx.x * 128, m0 = blockIdx.y * 128;
    f32x4 acc[4][4] = {};

    for (int k0 = 0; k0 < K; k0 += 32) {
        #pragma unroll
        for (int p = 0; p < 2; ++p) {
            int s = p * 256 + tid;
            int row = s >> 2;
            int sub = (s & 3) ^ ((row >> 1) & 3);
            gload_lds16(A + (size_t)(m0 + row) * K + k0 + sub * 8, &As[s * 8]);
            gload_lds16(B + (size_t)(n0 + row) * K + k0 + sub * 8, &Bs[s * 8]);
        }
        __syncthreads();
        f16x8 af[4], bfv[4];
        #pragma unroll
        for (int i = 0; i < 4; ++i) {
            int rowA = wr * 64 + i * 16 + (lane & 15);
            int slotA = (lane >> 4) ^ ((rowA >> 1) & 3);
            af[i] = *(const f16x8*)&As[rowA * 32 + slotA * 8];
            int rowB = wc * 64 + i * 16 + (lane & 15);
            int slotB = (lane >> 4) ^ ((rowB >> 1) & 3);
            bfv[i] = *(const f16x8*)&Bs[rowB * 32 + slotB * 8];
        }
        #pragma unroll
        for (int i = 0; i < 4; ++i)
            #pragma unroll
            for (int j = 0; j < 4; ++j)
                acc[i][j] = __builtin_amdgcn_mfma_f32_16x16x32_f16(af[i], bfv[j], acc[i][j], 0, 0, 0);
        __syncthreads();
    }

    #pragma unroll
    for (int i = 0; i < 4; ++i) {
        int mbase = m0 + wr * 64 + i * 16 + (lane >> 4) * 4;
        #pragma unroll
        for (int j = 0; j < 4; ++j) {
            int n = n0 + wc * 64 + j * 16 + (lane & 15);
            if (n < N) {
                #pragma unroll
                for (int r = 0; r < 4; ++r)
                    C[(size_t)(mbase + r) * N + n] = acc[i][j][r];
            }
        }
    }
}

// ---------------- conv / dt ----------------

// Sliding-window depthwise conv7 + bias + SiLU. Thread owns channel ch, walks
// CTL consecutive l; each raw element loaded exactly once (coalesced in ch).
__global__ __launch_bounds__(256) void conv_silu(const float* __restrict__ raw,
                                                 const float* __restrict__ cw,
                                                 const float* __restrict__ cb,
                                                 float* __restrict__ xbc) {
    int ch = blockIdx.x * 256 + threadIdx.x;
    if (ch >= CONVD) return;
    int l0 = blockIdx.y * CTL;
    int b = blockIdx.z;
    float wt[7];
    #pragma unroll
    for (int j = 0; j < 7; ++j) wt[j] = cw[ch * 7 + j];
    float bias = cb[ch];
    const float* rbase = raw + (size_t)b * LL * RAWC + ch;
    float win[7];
    #pragma unroll
    for (int j = 0; j < 6; ++j) {
        int lj = l0 - 3 + j;
        win[j] = (lj >= 0 && lj < LL) ? rbase[(size_t)lj * RAWC] : 0.f;
    }
    size_t obase = ((size_t)b * LL + l0) * CONVD + ch;
    for (int i = 0; i < CTL; ++i) {
        int lj = l0 + i + 3;
        win[6] = (lj < LL) ? rbase[(size_t)lj * RAWC] : 0.f;
        float acc = bias;
        #pragma unroll
        for (int j = 0; j < 7; ++j) acc += wt[j] * win[j];
        xbc[obase + (size_t)i * CONVD] = acc * sigmoidf_(acc);
        #pragma unroll
        for (int j = 0; j < 6; ++j) win[j] = win[j + 1];
    }
}

__global__ __launch_bounds__(256) void dt_kernel(const float* __restrict__ raw,
                                                 const float* __restrict__ dt_bias,
                                                 float* __restrict__ dtb) {
    int idx = blockIdx.x * 256 + threadIdx.x;
    if (idx >= BB * LL * NH) return;
    int h = idx & 31;
    int row = idx >> 5;
    float x = raw[(size_t)row * RAWC + CONVD + h] + dt_bias[h];
    dtb[idx] = softplusf_(x);
}

// ---------------- SSD ----------------

__device__ __forceinline__ float block_scan256(float v, float* sc, int tid) {
    sc[tid] = v;
    __syncthreads();
    for (int off = 1; off < 256; off <<= 1) {
        float t = 0.f;
        if (tid >= off) t = sc[tid - off];
        __syncthreads();
        sc[tid] += t;
        __syncthreads();
    }
    return sc[tid];
}

// G' tiles: G[l,s] = sum_n C[l,n]*B[s,n] per (bc), bf16 hi/lo, diag-masked,
// stored row-major (l*64+s) so s3 lanes can load A-fragments directly to regs.
__global__ __launch_bounds__(256) void g_mfma(const float* __restrict__ xbc,
                                              unsigned short* __restrict__ Gth,
                                              unsigned short* __restrict__ Gtl,
                                              int dir) {
    int lt = blockIdx.x, st = blockIdx.y, bc = blockIdx.z;
    if (st > lt) return;
    int b = bc / NC, c = bc % NC;
    int tid = threadIdx.x, lane = tid & 63, w = tid >> 6;
    __shared__ short Ch[4096], Cl[4096], Bh[4096], Bl[4096];
    #pragma unroll
    for (int i = 0; i < 16; ++i) {
        int e = tid + i * 256;
        int r = e >> 6, q = e & 63;
        int il = c * CK + lt * 64 + r;
        int tl = dir ? (LL - 1 - il) : il;
        float cv = xbc[((size_t)b * LL + tl) * CONVD + DI + NSTATE + q];
        unsigned short chh = f2bf(cv);
        Ch[swz(r, q)] = chh;
        Cl[swz(r, q)] = f2bf(cv - bf2f(chh));
        int is = c * CK + st * 64 + r;
        int ts = dir ? (LL - 1 - is) : is;
        float bv = xbc[((size_t)b * LL + ts) * CONVD + DI + q];
        unsigned short bhh = f2bf(bv);
        Bh[swz(r, q)] = bhh;
        Bl[swz(r, q)] = f2bf(bv - bf2f(bhh));
    }
    __syncthreads();
    f32x4 acc[4] = {};
    #pragma unroll
    for (int kk = 0; kk < 64; kk += 32) {
        int arow = w * 16 + (lane & 15);
        int aslot = ((kk >> 3) + (lane >> 4)) ^ (arow & 7);
        bf16x8 ah = *(const bf16x8*)&Ch[arow * 64 + aslot * 8];
        bf16x8 al = *(const bf16x8*)&Cl[arow * 64 + aslot * 8];
        #pragma unroll
        for (int j = 0; j < 4; ++j) {
            int brow = j * 16 + (lane & 15);
            int bslot = ((kk >> 3) + (lane >> 4)) ^ (brow & 7);
            bf16x8 bh = *(const bf16x8*)&Bh[brow * 64 + bslot * 8];
            bf16x8 bl = *(const bf16x8*)&Bl[brow * 64 + bslot * 8];
            acc[j] = __builtin_amdgcn_mfma_f32_16x16x32_bf16(ah, bh, acc[j], 0, 0, 0);
            acc[j] = __builtin_amdgcn_mfma_f32_16x16x32_bf16(ah, bl, acc[j], 0, 0, 0);
            acc[j] = __builtin_amdgcn_mfma_f32_16x16x32_bf16(al, bh, acc[j], 0, 0, 0);
        }
    }
    size_t tbase = ((size_t)bc * 10 + (size_t)(lt * (lt + 1) / 2 + st)) * 4096;
    #pragma unroll
    for (int j = 0; j < 4; ++j)
        #pragma unroll
        for (int rr = 0; rr < 4; ++rr) {
            int row = w * 16 + (lane >> 4) * 4 + rr;
            int col = j * 16 + (lane & 15);
            float g = acc[j][rr];
            if (lt == st && (col + dir > row)) g = 0.f;
            unsigned short hi = f2bf(g);
            int si = row * 64 + col;    // plain row-major (reg-fragment layout)
            Gth[tbase + si] = hi;
            Gtl[tbase + si] = f2bf(g - bf2f(hi));
        }
}

// states[p,n] = sum_s (w[s]*X[s,p]) * B[s,n]  via MFMA
__global__ __launch_bounds__(256) void s1_mfma(const float* __restrict__ xbc,
                                               const float* __restrict__ dtb,
                                               const float* __restrict__ A_log,
                                               float* __restrict__ states,
                                               float* __restrict__ csum, int dir) {
    int h = blockIdx.x, c = blockIdx.y, b = blockIdx.z;
    int tid = threadIdx.x, lane = tid & 63, w = tid >> 6;
    __shared__ float sc[256];
    {
        int gi = c * CK + tid;
        int t = dir ? (LL - 1 - gi) : gi;
        float A = -expf(A_log[h]);
        float dtv = dtb[((size_t)b * LL + t) * NH + h];
        float acum = block_scan256(dtv * A, sc, tid);
        float cs = sc[255];
        if (tid == 0) csum[(b * NC + c) * NH + h] = cs;
        float wgt = expf(cs - acum) * dtv;
        __syncthreads();
        sc[tid] = wgt;
        __syncthreads();
    }
    __shared__ short XTh[4096], XTl[4096], BTh[4096], BTl[4096];
    f32x4 acc[4] = {};
    #pragma unroll
    for (int st = 0; st < 4; ++st) {
        #pragma unroll
        for (int i = 0; i < 16; ++i) {
            int e = tid + i * 256;
            int r = e >> 6, q = e & 63;
            int gs = c * CK + st * 64 + r;
            int ts = dir ? (LL - 1 - gs) : gs;
            size_t rowb = ((size_t)b * LL + ts) * CONVD;
            float xv = xbc[rowb + h * 64 + q] * sc[st * 64 + r];
            unsigned short xh = f2bf(xv);
            XTh[swz(q, r)] = xh;
            XTl[swz(q, r)] = f2bf(xv - bf2f(xh));
            float bv = xbc[rowb + DI + q];
            unsigned short bh_ = f2bf(bv);
            BTh[swz(q, r)] = bh_;
            BTl[swz(q, r)] = f2bf(bv - bf2f(bh_));
        }
        __syncthreads();
        #pragma unroll
        for (int kk = 0; kk < 64; kk += 32) {
            int arow = w * 16 + (lane & 15);
            int aslot = ((kk >> 3) + (lane >> 4)) ^ (arow & 7);
            bf16x8 ah = *(const bf16x8*)&XTh[arow * 64 + aslot * 8];
            bf16x8 al = *(const bf16x8*)&XTl[arow * 64 + aslot * 8];
            #pragma unroll
            for (int j = 0; j < 4; ++j) {
                int brow = j * 16 + (lane & 15);
                int bslot = ((kk >> 3) + (lane >> 4)) ^ (brow & 7);
                bf16x8 bh = *(const bf16x8*)&BTh[brow * 64 + bslot * 8];
                bf16x8 bl = *(const bf16x8*)&BTl[brow * 64 + bslot * 8];
                acc[j] = __builtin_amdgcn_mfma_f32_16x16x32_bf16(ah, bh, acc[j], 0, 0, 0);
                acc[j] = __builtin_amdgcn_mfma_f32_16x16x32_bf16(ah, bl, acc[j], 0, 0, 0);
                acc[j] = __builtin_amdgcn_mfma_f32_16x16x32_bf16(al, bh, acc[j], 0, 0, 0);
            }
        }
        __syncthreads();
    }
    size_t base = (((size_t)(b * NC + c) * NH + h)) * 4096;
    #pragma unroll
    for (int j = 0; j < 4; ++j)
        #pragma unroll
        for (int rr = 0; rr < 4; ++rr) {
            int p = w * 16 + (lane >> 4) * 4 + rr;
            int n = j * 16 + (lane & 15);
            states[base + p * 64 + n] = acc[j][rr];
        }
}

__global__ __launch_bounds__(256) void s2_scan(float* __restrict__ states,
                                               const float* __restrict__ csum) {
    int h = blockIdx.x, b = blockIdx.y, eo = blockIdx.z;
    int e = eo * 256 + threadIdx.x;
    float run = 0.f;
    for (int z = 0; z < NC; ++z) {
        size_t base = (((size_t)(b * NC + z) * NH + h)) * (64 * 64);
        float s = states[base + e];
        states[base + e] = run;
        float g = expf(csum[(b * NC + z) * NH + h]);
        run = run * g + s;
    }
}

// s3 v3: G A-fragments loaded straight from global into registers (per-wave row
// slices, contiguous 16B per lane) — no G LDS, no manual vmcnt. X (B-operand)
// staged once in LDS. C fragments in regs too; only prev needs an LDS stage.
__global__ __launch_bounds__(256) void s3_reg(const float* __restrict__ xbc,
                                              const float* __restrict__ dtb,
                                              const float* __restrict__ A_log,
                                              const unsigned short* __restrict__ Gth,
                                              const unsigned short* __restrict__ Gtl,
                                              const float* __restrict__ prev,
                                              float* __restrict__ y, int dir, int beta) {
    int h = blockIdx.x, bc = blockIdx.y;
    int b = bc / NC, c = bc % NC;
    int tid = threadIdx.x, lane = tid & 63, w = tid >> 6;

    __shared__ short Xh[4][4096], Xl[4][4096];   // 64 KB: (Ein∘X)^T all 4 tiles
    __shared__ float sEl[256], sEin[256];

    // scan -> El, Ein (sEl doubles as scan scratch)
    {
        int gi = c * CK + tid;
        int t = dir ? (LL - 1 - gi) : gi;
        float A = -expf(A_log[h]);
        float dtv = dtb[((size_t)b * LL + t) * NH + h];
        float acum = block_scan256(dtv * A, sEl, tid);
        sEl[tid] = expf(acum);
        sEin[tid] = expf(-acum) * dtv;
    }
    __syncthreads();

    // stage all 4 X tiles
    #pragma unroll
    for (int st = 0; st < 4; ++st)
        #pragma unroll
        for (int i2 = 0; i2 < 16; ++i2) {
            int e = tid + i2 * 256;
            int r = e >> 6, q = e & 63;
            int gs = c * CK + st * 64 + r;
            int ts = dir ? (LL - 1 - gs) : gs;
            float xv = xbc[((size_t)b * LL + ts) * CONVD + h * 64 + q] * sEin[st * 64 + r];
            unsigned short xh = f2bf(xv);
            Xh[st][swz(q, r)] = xh;
            Xl[st][swz(q, r)] = f2bf(xv - bf2f(xh));
        }
    __syncthreads();

    f32x4 acc[4][4] = {};
    const int arow = w * 16 + (lane & 15);
    const int kofs = (lane >> 4) * 8;
    constexpr int ph_lq[10] = {0, 1, 2, 3, 1, 2, 3, 2, 3, 3};
    constexpr int ph_st[10] = {0, 0, 0, 0, 1, 1, 1, 2, 2, 3};
    #pragma unroll
    for (int i = 0; i < 10; ++i) {
        const int lq = ph_lq[i], st = ph_st[i];
        size_t tb = ((size_t)bc * 10 + (size_t)(lq * (lq + 1) / 2 + st)) * 4096
                  + (size_t)arow * 64 + kofs;
        bf16x8 ah0 = *(const bf16x8*)(Gth + tb);
        bf16x8 ah1 = *(const bf16x8*)(Gth + tb + 32);
        bf16x8 al0 = *(const bf16x8*)(Gtl + tb);
        bf16x8 al1 = *(const bf16x8*)(Gtl + tb + 32);
        #pragma unroll
        for (int j = 0; j < 4; ++j) {
            int brow = j * 16 + (lane & 15);
            int t0 = (lane >> 4) ^ (brow & 7);
            int t1 = (4 + (lane >> 4)) ^ (brow & 7);
            bf16x8 bh0 = *(const bf16x8*)&Xh[st][brow * 64 + t0 * 8];
            bf16x8 bl0 = *(const bf16x8*)&Xl[st][brow * 64 + t0 * 8];
            bf16x8 bh1 = *(const bf16x8*)&Xh[st][brow * 64 + t1 * 8];
            bf16x8 bl1 = *(const bf16x8*)&Xl[st][brow * 64 + t1 * 8];
            acc[lq][j] = __builtin_amdgcn_mfma_f32_16x16x32_bf16(ah0, bh0, acc[lq][j], 0, 0, 0);
            acc[lq][j] = __builtin_amdgcn_mfma_f32_16x16x32_bf16(ah0, bl0, acc[lq][j], 0, 0, 0);
            acc[lq][j] = __builtin_amdgcn_mfma_f32_16x16x32_bf16(al0, bh0, acc[lq][j], 0, 0, 0);
            acc[lq][j] = __builtin_amdgcn_mfma_f32_16x16x32_bf16(ah1, bh1, acc[lq][j], 0, 0, 0);
            acc[lq][j] = __builtin_amdgcn_mfma_f32_16x16x32_bf16(ah1, bl1, acc[lq][j], 0, 0, 0);
            acc[lq][j] = __builtin_amdgcn_mfma_f32_16x16x32_bf16(al1, bh1, acc[lq][j], 0, 0, 0);
        }
    }

    // ---- Y_off: A = C(lq) in regs (per-lane global loads), B-op = prev in X slot 0 ----
    __syncthreads();   // main loop's X reads done before overwrite
    {
        size_t pbase = ((size_t)bc * NH + h) * 4096;
        #pragma unroll
        for (int i2 = 0; i2 < 16; ++i2) {
            int e = tid + i2 * 256;
            int r = e >> 6, q = e & 63;
            float pv = prev[pbase + r * 64 + q];
            unsigned short ph = f2bf(pv);
            Xh[0][swz(r, q)] = ph;
            Xl[0][swz(r, q)] = f2bf(pv - bf2f(ph));
        }
    }
    __syncthreads();
    #pragma unroll
    for (int lq = 0; lq < 4; ++lq) {
        int il = c * CK + lq * 64 + arow;
        int tl = dir ? (LL - 1 - il) : il;
        const float* cp = xbc + ((size_t)b * LL + tl) * CONVD + DI + NSTATE;
        bf16x8 ah0, al0, ah1, al1;
        #pragma unroll
        for (int e = 0; e < 8; ++e) {
            float c0 = cp[kofs + e];
            float c1 = cp[32 + kofs + e];
            unsigned short hh = f2bf(c0);
            ah0[e] = (short)hh; al0[e] = (short)f2bf(c0 - bf2f(hh));
            hh = f2bf(c1);
            ah1[e] = (short)hh; al1[e] = (short)f2bf(c1 - bf2f(hh));
        }
        #pragma unroll
        for (int j = 0; j < 4; ++j) {
            int brow = j * 16 + (lane & 15);
            int t0 = (lane >> 4) ^ (brow & 7);
            int t1 = (4 + (lane >> 4)) ^ (brow & 7);
            bf16x8 bh0 = *(const bf16x8*)&Xh[0][brow * 64 + t0 * 8];
            bf16x8 bl0 = *(const bf16x8*)&Xl[0][brow * 64 + t0 * 8];
            bf16x8 bh1 = *(const bf16x8*)&Xh[0][brow * 64 + t1 * 8];
            bf16x8 bl1 = *(const bf16x8*)&Xl[0][brow * 64 + t1 * 8];
            acc[lq][j] = __builtin_amdgcn_mfma_f32_16x16x32_bf16(ah0, bh0, acc[lq][j], 0, 0, 0);
            acc[lq][j] = __builtin_amdgcn_mfma_f32_16x16x32_bf16(ah0, bl0, acc[lq][j], 0, 0, 0);
            acc[lq][j] = __builtin_amdgcn_mfma_f32_16x16x32_bf16(al0, bh0, acc[lq][j], 0, 0, 0);
            acc[lq][j] = __builtin_amdgcn_mfma_f32_16x16x32_bf16(ah1, bh1, acc[lq][j], 0, 0, 0);
            acc[lq][j] = __builtin_amdgcn_mfma_f32_16x16x32_bf16(ah1, bl1, acc[lq][j], 0, 0, 0);
            acc[lq][j] = __builtin_amdgcn_mfma_f32_16x16x32_bf16(al1, bh1, acc[lq][j], 0, 0, 0);
        }
    }

    // epilogue: scale by El[l], store/accumulate
    #pragma unroll
    for (int lq = 0; lq < 4; ++lq)
        #pragma unroll
        for (int j = 0; j < 4; ++j)
            #pragma unroll
            for (int rr = 0; rr < 4; ++rr) {
                int ll = lq * 64 + w * 16 + (lane >> 4) * 4 + rr;
                int il = c * CK + ll;
                int tl = dir ? (LL - 1 - il) : il;
                size_t yb = ((size_t)b * LL + tl) * DI + h * 64 + j * 16 + (lane & 15);
                float v = sEl[ll] * acc[lq][j][rr];
                if (beta) y[yb] += v;
                else      y[yb]  = v;
            }
}

// RMSNorm + silu(z) gate, fused fp16 output (feeds out_proj GEMM directly).
__global__ __launch_bounds__(256) void norm_gate16(const float* __restrict__ zbuf,
                                                   const float* __restrict__ norm_w,
                                                   const float* __restrict__ y,
                                                   _Float16* __restrict__ y16) {
    int row = blockIdx.x;
    int tid = threadIdx.x;
    float ss = 0.f;
    size_t yb = (size_t)row * DI;
    for (int i = tid; i < DI; i += 256) {
        float v = y[yb + i];
        ss += v * v;
    }
    #pragma unroll
    for (int off = 32; off > 0; off >>= 1) ss += __shfl_down(ss, off, 64);
    __shared__ float red[4];
    if ((tid & 63) == 0) red[tid >> 6] = ss;
    __syncthreads();
    float tot = red[0] + red[1] + red[2] + red[3];
    float rstd = rsqrtf(tot / DI + 1e-5f);
    for (int i = tid; i < DI; i += 256) {
        float z = zbuf[yb + i];
        float g = z * sigmoidf_(z);
        y16[yb + i] = (_Float16)(y[yb + i] * rstd * norm_w[i] * g);
    }
}

extern "C" void kernel_launch(void* const* d_in, const int* in_sizes, int n_in,
                              void* d_out, int out_size, void* d_ws, size_t ws_size,
                              hipStream_t stream) {
    const float* u          = (const float*)d_in[0];
    const float* in_proj_w  = (const float*)d_in[1];
    const float* conv_w     = (const float*)d_in[2];
    const float* conv_b     = (const float*)d_in[3];
    const float* dt_bias    = (const float*)d_in[4];
    const float* A_log      = (const float*)d_in[5];
    const float* norm_w     = (const float*)d_in[6];
    const float* out_proj_w = (const float*)d_in[7];
    float* out = (float*)d_out;

    float* ws  = (float*)d_ws;
    float* z   = ws;                               // 16,777,216 f
    float* raw = z + (size_t)BB * LL * DI;         // 18,087,936 f
    float* xbc = raw + (size_t)BB * LL * RAWC;     // 17,825,792 f
    float* y   = raw;                              // alias: raw dead after conv+dt

    // fp16 pack buffers in dead regions:
    _Float16* u16    = (_Float16*)d_out;                 // 16.8 MB (d_out free pre-SSD)
    _Float16* w16z   = (_Float16*)xbc;                   // 4.2 MB (xbc not yet live)
    _Float16* w16raw = w16z + (size_t)2048 * 1024;       // 4.7 MB
    // post-SSD (xbc dead): out_proj weight + fused-norm fp16 y
    _Float16* w16out = (_Float16*)xbc;                   // 1024x2048 = 4.2 MB
    _Float16* y16    = w16out + (size_t)1024 * 2048;     // 8192x2048 = 33.5 MB (fits in xbc's 71 MB)

    // SSD scratch in d_out (u16 dead by then; overwritten by final GEMM at end)
    float* states        = (float*)d_out;                         // 4,194,304 f
    unsigned short* Gth  = (unsigned short*)(states + 4194304);   // 2,621,440 sh
    unsigned short* Gtl  = Gth + 2621440;                         // 2,621,440 sh
    float* dtb           = (float*)(Gtl + 2621440);               //   262,144 f
    float* csum          = dtb + 262144;                          //     1,024 f
    float* prev          = states;

    dim3 blk(256);
    int M = BB * LL;

    // 0) fp16 packs for in_proj
    pack_a16<<<(M * DM + 255) / 256, blk, 0, stream>>>(u, u16, M * DM);
    pack_w16<<<(2048 * DM + 255) / 256, blk, 0, stream>>>(in_proj_w, w16z, 2048, 2048, DM);
    pack_w16<<<(2304 * DM + 255) / 256, blk, 0, stream>>>(in_proj_w + (size_t)DI * DM, w16raw, RAWC, 2304, DM);
    // 1) in_proj GEMMs (fp16)
    gemm_f16<<<dim3(2048 / 128, M / 128), blk, 0, stream>>>(u16, w16z, z, M, 2048, DM);
    gemm_f16<<<dim3(2304 / 128, M / 128), blk, 0, stream>>>(u16, w16raw, raw, M, RAWC, DM);
    // 2) sliding-window conv + silu ; 3) dt
    conv_silu<<<dim3((CONVD + 255) / 256, LL / CTL, BB), blk, 0, stream>>>(raw, conv_w, conv_b, xbc);
    dt_kernel<<<(BB * LL * NH + 255) / 256, blk, 0, stream>>>(raw, dt_bias, dtb);
    // 4) bidirectional SSD
    for (int dir = 0; dir < 2; ++dir) {
        g_mfma<<<dim3(4, 4, BB * NC), blk, 0, stream>>>(xbc, Gth, Gtl, dir);
        s1_mfma<<<dim3(NH, NC, BB), blk, 0, stream>>>(xbc, dtb, A_log, states, csum, dir);
        s2_scan<<<dim3(NH, BB, 16), blk, 0, stream>>>(states, csum);
        s3_reg<<<dim3(NH, BB * NC), blk, 0, stream>>>(xbc, dtb, A_log, Gth, Gtl, prev, y, dir, dir);
    }
    // 5) RMSNorm + gate, fused fp16 pack of y
    norm_gate16<<<M, blk, 0, stream>>>(z, norm_w, y, y16);
    // 6) out_proj (fp16)
    pack_a16<<<(DM * DI + 255) / 256, blk, 0, stream>>>(out_proj_w, w16out, DM * DI);
    gemm_f16<<<dim3(1024 / 128, M / 128), blk, 0, stream>>>(y16, w16out, out, M, DM, DI);
}